// Round 2
// baseline (166.602 us; speedup 1.0000x reference)
//
#include <hip/hip_runtime.h>

// CuriosityEngine: the goal_sampler path (32x replicated bottleneck + argmax)
// is output-invariant — all 32 action slices are bit-identical, so
// argmax(predicted_entropy) == 0 always. Only the surprise head matters:
//   surprise = relu(mean_T(x).reshape(B,2D) @ W1 + b1) @ W2 + b2   -> (B,)
//   best_action_idx = 0                                            -> scalar
//
// x: (B=4, T=2048, D=768, 2) fp32 => rows of R=1536 floats, reduce over T.
//
// Structure (2 kernels, no atomics, no memset):
//   K1: partial column sums over T-chunks -> ws   (HBM-bound 50 MB pass)
//   K2: per-batch block: reduce partials -> LDS sf, GEMV 1536->256,
//       ReLU . W2 reduce, write out[0..3] and out[4]=0.

#define BB 4
#define TT 2048
#define RR 1536        // 2*D
#define HH 256
#define NCHUNK 128     // T-chunks; 512 blocks total = 2/CU
#define ROWSPC (TT / NCHUNK)   // 16 rows per chunk

// ---- Kernel 1: partial column sums, fully coalesced, write-only output ----
__global__ __launch_bounds__(384) void colsum_part_kernel(const float* __restrict__ x,
                                                          float* __restrict__ part) {
    const int chunk = blockIdx.x;           // 0..NCHUNK-1
    const int b     = blockIdx.y;
    const int c     = threadIdx.x;          // float4 column 0..383
    const float4* xb = (const float4*)(x + (size_t)b * TT * RR);
    float4 acc = make_float4(0.f, 0.f, 0.f, 0.f);
    const int t0 = chunk * ROWSPC;
    #pragma unroll
    for (int tt = 0; tt < ROWSPC; ++tt) {
        float4 v = xb[(size_t)(t0 + tt) * (RR / 4) + c];
        acc.x += v.x; acc.y += v.y; acc.z += v.z; acc.w += v.w;
    }
    // part[b][chunk][c] as float4, coalesced write, no RMW
    ((float4*)part)[(size_t)(b * NCHUNK + chunk) * (RR / 4) + c] = acc;
}

// ---- Kernel 2: fused reduce + MLP head, one block per batch ----
__global__ __launch_bounds__(256) void mlp_head_kernel(const float* __restrict__ part,
                                                       const float* __restrict__ W1,
                                                       const float* __restrict__ b1,
                                                       const float* __restrict__ W2,
                                                       const float* __restrict__ b2,
                                                       float* __restrict__ out) {
    __shared__ float sf[RR];     // mean-over-T state row for this batch
    __shared__ float red[4];
    const int b   = blockIdx.x;
    const int tid = threadIdx.x;

    // Step A: reduce NCHUNK partials per column into LDS (scaled by 1/T).
    const float4* pb = (const float4*)(part + (size_t)b * NCHUNK * RR);
    const float inv_t = 1.0f / (float)TT;
    for (int col = tid; col < RR / 4; col += 256) {
        float4 acc = make_float4(0.f, 0.f, 0.f, 0.f);
        #pragma unroll 8
        for (int k = 0; k < NCHUNK; ++k) {
            float4 v = pb[(size_t)k * (RR / 4) + col];   // coalesced across threads
            acc.x += v.x; acc.y += v.y; acc.z += v.z; acc.w += v.w;
        }
        acc.x *= inv_t; acc.y *= inv_t; acc.z *= inv_t; acc.w *= inv_t;
        ((float4*)sf)[col] = acc;
    }
    __syncthreads();

    // Step B: hid[h] = b1[h] + sum_j sf[j] * W1[j][h]; thread == h, W1 coalesced,
    // sf[j] is an LDS same-address broadcast (conflict-free).
    float acc = b1[tid];
    #pragma unroll 8
    for (int j = 0; j < RR; ++j) {
        acc += sf[j] * W1[(size_t)j * HH + tid];
    }

    // Step C: relu, dot with W2, block reduce, epilogue.
    float v = fmaxf(acc, 0.f) * W2[tid];
    #pragma unroll
    for (int off = 32; off > 0; off >>= 1) v += __shfl_down(v, off, 64);
    const int lane = tid & 63, wave = tid >> 6;
    if (lane == 0) red[wave] = v;
    __syncthreads();
    if (tid == 0) {
        out[b] = red[0] + red[1] + red[2] + red[3] + b2[0];
        if (b == 0) {
            // best_action_idx: argmax over 32 bit-identical entropies == 0.
            // 0x00000000 is valid under either f32 or i32 readback.
            out[4] = 0.0f;
        }
    }
}

extern "C" void kernel_launch(void* const* d_in, const int* in_sizes, int n_in,
                              void* d_out, int out_size, void* d_ws, size_t ws_size,
                              hipStream_t stream) {
    const float* x  = (const float*)d_in[0];
    const float* W1 = (const float*)d_in[1];
    const float* b1 = (const float*)d_in[2];
    const float* W2 = (const float*)d_in[3];
    const float* b2 = (const float*)d_in[4];
    // d_in[5..8] (Wd, bd, Wu, bu) unused: bottleneck path is output-invariant.

    float* part = (float*)d_ws;   // B * NCHUNK * RR fp32 partial sums (~3.1 MB)

    colsum_part_kernel<<<dim3(NCHUNK, BB), 384, 0, stream>>>(x, part);
    mlp_head_kernel<<<dim3(BB), 256, 0, stream>>>(part, W1, b1, W2, b2, (float*)d_out);
}

// Round 3
// 102.445 us; speedup vs baseline: 1.6263x; 1.6263x over previous
//
#include <hip/hip_runtime.h>

// CuriosityEngine: the goal_sampler path (32x replicated bottleneck + argmax)
// is output-invariant — all 32 action slices are bit-identical, so
// argmax(predicted_entropy) == 0 always. Only the surprise head matters:
//   surprise = relu(mean_T(x).reshape(B,2D) @ W1 + b1) @ W2 + b2   -> (B,)
//   best_action_idx = 0                                            -> scalar
//
// x: (B=4, T=2048, D=768, 2) fp32 => rows of R=1536 floats, reduce over T.
//
// R2 post-mortem: fusing the head into 4 blocks was latency-suicide (90 µs at
// 0.17% occupancy). This version spreads every stage wide enough to hide
// latency with TLP; serial per-thread load depth <= ~72 everywhere.

#define BB 4
#define TT 2048
#define RR 1536        // 2*D
#define HH 256
#define NCHUNK 128     // T-chunks for K1; 512 blocks = 2/CU
#define ROWSPC (TT / NCHUNK)   // 16 rows per chunk
#define NJC 24         // j-chunks for K2 (1536 / 64)
#define JCW 64         // j's per chunk

// ---- Kernel 1: partial column sums, fully coalesced, write-only output ----
__global__ __launch_bounds__(384) void colsum_part_kernel(const float* __restrict__ x,
                                                          float* __restrict__ part) {
    const int chunk = blockIdx.x;           // 0..NCHUNK-1
    const int b     = blockIdx.y;
    const int c     = threadIdx.x;          // float4 column 0..383
    const float4* xb = (const float4*)(x + (size_t)b * TT * RR);
    float4 acc = make_float4(0.f, 0.f, 0.f, 0.f);
    const int t0 = chunk * ROWSPC;
    #pragma unroll
    for (int tt = 0; tt < ROWSPC; ++tt) {
        float4 v = xb[(size_t)(t0 + tt) * (RR / 4) + c];
        acc.x += v.x; acc.y += v.y; acc.z += v.z; acc.w += v.w;
    }
    ((float4*)part)[(size_t)(b * NCHUNK + chunk) * (RR / 4) + c] = acc;
}

// ---- Kernel 2: per (j-chunk, b): reduce partials for 64 j's, then GEMV slice.
// 96 blocks x 256 threads. Writes hpart[b][jc][h].
__global__ __launch_bounds__(256) void hidden_part_kernel(const float* __restrict__ part,
                                                          const float* __restrict__ W1,
                                                          float* __restrict__ hpart) {
    const int jc  = blockIdx.x;             // 0..NJC-1
    const int b   = blockIdx.y;
    const int tid = threadIdx.x;

    // Step A: reduce NCHUNK partials for this block's 16 float4 columns.
    // 256 threads = 16 cols x 16 chunk-groups (8 chunks each).
    __shared__ float4 red4[16][16];         // [kgroup][col_local]
    __shared__ float  sf[JCW];              // mean-scaled slice
    const int col_l = tid & 15;             // 0..15
    const int kg    = tid >> 4;             // 0..15
    const float4* pb = (const float4*)(part + (size_t)b * NCHUNK * RR);
    const int col = jc * 16 + col_l;        // global float4 column
    float4 acc = make_float4(0.f, 0.f, 0.f, 0.f);
    #pragma unroll
    for (int i = 0; i < 8; ++i) {
        const int k = kg * 8 + i;
        float4 v = pb[(size_t)k * (RR / 4) + col];
        acc.x += v.x; acc.y += v.y; acc.z += v.z; acc.w += v.w;
    }
    red4[kg][col_l] = acc;
    __syncthreads();
    if (tid < 16) {                          // one thread per col_local
        float4 s = make_float4(0.f, 0.f, 0.f, 0.f);
        #pragma unroll
        for (int g = 0; g < 16; ++g) {
            float4 v = red4[g][tid];
            s.x += v.x; s.y += v.y; s.z += v.z; s.w += v.w;
        }
        const float inv_t = 1.0f / (float)TT;
        sf[tid * 4 + 0] = s.x * inv_t;
        sf[tid * 4 + 1] = s.y * inv_t;
        sf[tid * 4 + 2] = s.z * inv_t;
        sf[tid * 4 + 3] = s.w * inv_t;
    }
    __syncthreads();

    // Step B: hpart[h] = sum_{j in slice} sf[j] * W1[j][h]; thread == h.
    // W1 coalesced across threads; sf is LDS broadcast (conflict-free).
    const int jbase = jc * JCW;
    float hacc = 0.f;
    #pragma unroll 8
    for (int j = 0; j < JCW; ++j) {
        hacc += sf[j] * W1[(size_t)(jbase + j) * HH + tid];
    }
    hpart[((size_t)b * NJC + jc) * HH + tid] = hacc;
}

// ---- Kernel 3: sum hpart over jc, + b1, relu, dot W2, epilogue ----
__global__ __launch_bounds__(256) void out_kernel(const float* __restrict__ hpart,
                                                  const float* __restrict__ b1,
                                                  const float* __restrict__ W2,
                                                  const float* __restrict__ b2,
                                                  float* __restrict__ out) {
    const int b   = blockIdx.x;
    const int tid = threadIdx.x;
    float acc = b1[tid];
    const float* hp = hpart + (size_t)b * NJC * HH;
    #pragma unroll
    for (int jc = 0; jc < NJC; ++jc) {
        acc += hp[jc * HH + tid];            // coalesced across threads
    }
    float v = fmaxf(acc, 0.f) * W2[tid];
    #pragma unroll
    for (int off = 32; off > 0; off >>= 1) v += __shfl_down(v, off, 64);
    __shared__ float red[4];
    const int lane = tid & 63, wave = tid >> 6;
    if (lane == 0) red[wave] = v;
    __syncthreads();
    if (tid == 0) {
        out[b] = red[0] + red[1] + red[2] + red[3] + b2[0];
        if (b == 0) {
            // best_action_idx: argmax over 32 bit-identical entropies == 0.
            // 0x00000000 is valid under either f32 or i32 readback.
            out[4] = 0.0f;
        }
    }
}

extern "C" void kernel_launch(void* const* d_in, const int* in_sizes, int n_in,
                              void* d_out, int out_size, void* d_ws, size_t ws_size,
                              hipStream_t stream) {
    const float* x  = (const float*)d_in[0];
    const float* W1 = (const float*)d_in[1];
    const float* b1 = (const float*)d_in[2];
    const float* W2 = (const float*)d_in[3];
    const float* b2 = (const float*)d_in[4];
    // d_in[5..8] (Wd, bd, Wu, bu) unused: bottleneck path is output-invariant.

    float* part  = (float*)d_ws;                    // B*NCHUNK*RR fp32 (~3.1 MB)
    float* hpart = part + (size_t)BB * NCHUNK * RR; // B*NJC*HH fp32 (~96 KB)

    colsum_part_kernel<<<dim3(NCHUNK, BB), 384, 0, stream>>>(x, part);
    hidden_part_kernel<<<dim3(NJC, BB), 256, 0, stream>>>(part, W1, hpart);
    out_kernel<<<dim3(BB), 256, 0, stream>>>(hpart, b1, W2, b2, (float*)d_out);
}

// Round 4
// 101.326 us; speedup vs baseline: 1.6442x; 1.0110x over previous
//
#include <hip/hip_runtime.h>

// CuriosityEngine: the goal_sampler path (32x replicated bottleneck + argmax)
// is output-invariant — all 32 action slices are bit-identical, so
// argmax(predicted_entropy) == 0 always. Only the surprise head matters:
//   surprise = relu(mean_T(x).reshape(B,2D) @ W1 + b1) @ W2 + b2   -> (B,)
//   best_action_idx = 0                                            -> scalar
//
// x: (B=4, T=2048, D=768, 2) fp32 => rows of R=1536 floats, reduce over T.
//
// R3 post-mortem: K2(96 blk)+K3(4 blk) cost ~26 µs — tiny kernels have a
// 5-15 µs floor each. This version is 2 dispatches: K1' fuses T-reduce +
// W1-GEMV-slice (no intermediate colsum round-trip), K2' fuses the rest.

#define BB 4
#define TT 2048
#define RR 1536        // 2*D
#define HH 256
#define NJC 24         // j-chunks (1536/64)
#define JCW 64         // j's per chunk (16 float4)
#define NTC 8          // t-chunks
#define TCH (TT / NTC) // 256 rows per t-chunk
#define NS  (NJC * NTC) // 192 hpart slices per b

// ---- Kernel 1: per (jc, tc, b): reduce 256 rows of a 64-col slice of x,
// then GEMV that 64-vector against W1[jc-slice] -> hpart[s][b][0:256].
// 768 blocks x 256 threads. x reads: 4 rows x 256 B contiguous per wave
// instruction (100% cache-line utilization). W1 slice (64 KB) is L2-resident
// and reused by the 32 blocks sharing jc.
__global__ __launch_bounds__(256) void fused_colsum_gemv_kernel(
        const float* __restrict__ x, const float* __restrict__ W1,
        float* __restrict__ hpart) {
    const int jc  = blockIdx.x;            // 0..NJC-1
    const int tc  = blockIdx.y;            // 0..NTC-1
    const int b   = blockIdx.z;
    const int tid = threadIdx.x;

    __shared__ float4 red4[16][16];        // [rowgrp][col_local]
    __shared__ float  sfl[JCW];            // mean-scaled j-slice

    // Load/reduce phase: thread = (rowl 0..15, colf4 0..15); 16 passes.
    const int rowl  = tid >> 4;
    const int colf4 = tid & 15;
    const float4* xb = (const float4*)(x + (size_t)b * TT * RR);
    const int t0  = tc * TCH;
    const int col = jc * 16 + colf4;       // global float4 column
    float4 acc = make_float4(0.f, 0.f, 0.f, 0.f);
    #pragma unroll
    for (int pass = 0; pass < 16; ++pass) {
        const int t = t0 + pass * 16 + rowl;
        float4 v = xb[(size_t)t * (RR / 4) + col];
        acc.x += v.x; acc.y += v.y; acc.z += v.z; acc.w += v.w;
    }
    red4[rowl][colf4] = acc;
    __syncthreads();
    if (tid < 16) {
        float4 s = make_float4(0.f, 0.f, 0.f, 0.f);
        #pragma unroll
        for (int r = 0; r < 16; ++r) {
            float4 v = red4[r][tid];
            s.x += v.x; s.y += v.y; s.z += v.z; s.w += v.w;
        }
        const float inv_t = 1.0f / (float)TT;
        sfl[tid * 4 + 0] = s.x * inv_t;
        sfl[tid * 4 + 1] = s.y * inv_t;
        sfl[tid * 4 + 2] = s.z * inv_t;
        sfl[tid * 4 + 3] = s.w * inv_t;
    }
    __syncthreads();

    // GEMV slice: thread == h; W1 coalesced, sfl LDS broadcast.
    const int jbase = jc * JCW;
    float hacc = 0.f;
    #pragma unroll 8
    for (int j = 0; j < JCW; ++j) {
        hacc += sfl[j] * W1[(size_t)(jbase + j) * HH + tid];
    }
    const int s_idx = jc * NTC + tc;
    hpart[((size_t)s_idx * BB + b) * HH + tid] = hacc;
}

// ---- Kernel 2: sum 192 hpart slices (4-way split over s), + b1, relu,
// dot W2, reduce, epilogue. 4 blocks x 1024 threads (16 waves). ----
__global__ __launch_bounds__(1024) void head_kernel(
        const float* __restrict__ hpart, const float* __restrict__ b1,
        const float* __restrict__ W2, const float* __restrict__ b2,
        float* __restrict__ out) {
    const int b   = blockIdx.x;
    const int tid = threadIdx.x;
    const int h   = tid & (HH - 1);
    const int g   = tid >> 8;              // 0..3 s-group

    __shared__ float partial[4][HH];
    __shared__ float red[16];

    float acc = 0.f;
    #pragma unroll 12
    for (int s = g * (NS / 4); s < (g + 1) * (NS / 4); ++s) {
        acc += hpart[((size_t)s * BB + b) * HH + h];   // coalesced
    }
    partial[g][h] = acc;
    __syncthreads();

    float v = 0.f;
    if (tid < HH) {
        float hsum = partial[0][tid] + partial[1][tid] +
                     partial[2][tid] + partial[3][tid] + b1[tid];
        v = fmaxf(hsum, 0.f) * W2[tid];
    }
    #pragma unroll
    for (int off = 32; off > 0; off >>= 1) v += __shfl_down(v, off, 64);
    const int lane = tid & 63, wave = tid >> 6;
    if (lane == 0) red[wave] = v;
    __syncthreads();
    if (tid == 0) {
        float s = 0.f;
        #pragma unroll
        for (int w = 0; w < 4; ++w) s += red[w];   // waves 4..15 hold zeros
        out[b] = s + b2[0];
        if (b == 0) {
            // best_action_idx: argmax over 32 bit-identical entropies == 0.
            // 0x00000000 is valid under either f32 or i32 readback.
            out[4] = 0.0f;
        }
    }
}

extern "C" void kernel_launch(void* const* d_in, const int* in_sizes, int n_in,
                              void* d_out, int out_size, void* d_ws, size_t ws_size,
                              hipStream_t stream) {
    const float* x  = (const float*)d_in[0];
    const float* W1 = (const float*)d_in[1];
    const float* b1 = (const float*)d_in[2];
    const float* W2 = (const float*)d_in[3];
    const float* b2 = (const float*)d_in[4];
    // d_in[5..8] (Wd, bd, Wu, bu) unused: bottleneck path is output-invariant.

    float* hpart = (float*)d_ws;   // NS * BB * HH fp32 (~786 KB)

    fused_colsum_gemv_kernel<<<dim3(NJC, NTC, BB), 256, 0, stream>>>(x, W1, hpart);
    head_kernel<<<dim3(BB), 1024, 0, stream>>>(hpart, b1, W2, b2, (float*)d_out);
}